// Round 15
// baseline (830.121 us; speedup 1.0000x reference)
//
#include <hip/hip_runtime.h>

#define TLEN  1024
#define HN    64
#define LOG2E 1.4426950408889634f

// clang builtins use __fp16 vectors, NOT _Float16.
typedef __fp16 half2v __attribute__((ext_vector_type(2)));
typedef __fp16 half8v __attribute__((ext_vector_type(8)));
typedef float  float4v __attribute__((ext_vector_type(4)));

// E=4 BATCHED RECURRENCES PER WAVE. 256 blocks x 64 thr; block handles
// batch elements b0..b0+3.
//
// Synthesis of R3..R14: every single-recurrence variant (fdot2 524,
// MFMA 508, interleave 510, pk_fma 533) hits the same wall: ~1200 cy/step
// of which only ~450-490 is real issue (VALUBusy/2) -- ~750 cy is exposed
// dependency latency with nothing to fill it (1 recurrence/wave). R13
// proved scheduling can't fix it; R9 proved extra waves+barriers can't.
// Fix: FOUR independent recurrences in one wave. MFMA makes the batching
// free: the same 32 MFMA that served 1 element serve 16 A-rows.
//   A row 4m = h of element m  =>  D row 4m = reg 0 of k-group m
//   (D layout col=lane&15, row=(lane>>4)*4+reg -- m89/R10-verified), so
//   lane (rg,col) holds element rg's gate t*16+col in d_t[0]: compile-time
//   reg index, NO cndmask, NO LDS dump. Rows r%4!=0 are garbage-in,
//   garbage-out (D row m depends only on A row m).
// Per lane: element rg, 4 cells (units c*16+col, c=0..3): i-gate = tile c,
// f = 4+c, g = 8+c, o = 12+c (row c*16+col). 4 independent act chains
// hide each other's latency; all 64 lanes uniform (no divergence).
// x path: staged per-element in LDS (xbuf), read per step by uniform
// per-rg ds_read_b64 -- readlanes eliminated. 32 x-fdot2/lane (4 units).
// h publish: 4 ds_write_b16 into element rg's h vector (stride-88 f16
// padding de-conflicts A-reads); next step's A reads are same-wave
// in-order DS (R11/R14-verified pattern).
// All MFMA layout assumptions HW-verified by R10+R11 passes. Per-cell
// math == R11 exactly => absmax must be exactly 0.0009765625 (tripwire).
// FC: per-lane 4-term partial -> ring[s][e][col] -> chunk-end transposed
// reduce (16 steps/chunk), coalesced stores.

#define FOR16(X) \
    X(0) X(1) X(2) X(3) X(4) X(5) X(6) X(7) \
    X(8) X(9) X(10) X(11) X(12) X(13) X(14) X(15)
#define FORC(X) X(0) X(1) X(2) X(3)

__global__ __launch_bounds__(64, 1)
void lstm_e4(const float* __restrict__ x,      // [B, T, 4]
             const float* __restrict__ W_ih,   // [256, 4]
             const float* __restrict__ W_hh,   // [256, 64]
             const float* __restrict__ b_ih,   // [256]
             const float* __restrict__ b_hh,   // [256]
             const float* __restrict__ W_fc,   // [1, 64]
             const float* __restrict__ b_fc,   // [1]
             float* __restrict__ out)          // [B, T]
{
    const int b0  = blockIdx.x * 4;
    const int l   = threadIdx.x;
    const int col = l & 15;        // A row / B col / D col
    const int rg  = l >> 4;        // k-group; THIS LANE'S ELEMENT

    __shared__ alignas(16) unsigned short hbuf[4 * 88];  // h[e][u], pad 88
    __shared__ alignas(16) unsigned int   xbuf[4 * 34];  // x[e][s][2], pad 34
    __shared__ alignas(16) float          ring[16 * 80]; // [s][e*20+col]

    for (int i = l; i < 4 * 88; i += 64) hbuf[i] = 0;    // h_0 = 0

    // ---- B fragments: 16 tiles x 2 K-halves, W rows as COLUMNS (R11) ----
#define DECLW(t) half8v wb##t##_0, wb##t##_1;
    FOR16(DECLW)
#undef DECLW
#define LOADW(t) { \
    const float sc = (((t) >> 2) == 2) ? (2.0f * LOG2E) : LOG2E; \
    const float* wr = W_hh + ((t) * 16 + col) * HN + rg * 8; \
    wb##t##_0[0] = (__fp16)(wr[0] * sc);  wb##t##_0[1] = (__fp16)(wr[1] * sc); \
    wb##t##_0[2] = (__fp16)(wr[2] * sc);  wb##t##_0[3] = (__fp16)(wr[3] * sc); \
    wb##t##_0[4] = (__fp16)(wr[4] * sc);  wb##t##_0[5] = (__fp16)(wr[5] * sc); \
    wb##t##_0[6] = (__fp16)(wr[6] * sc);  wb##t##_0[7] = (__fp16)(wr[7] * sc); \
    wb##t##_1[0] = (__fp16)(wr[32] * sc); wb##t##_1[1] = (__fp16)(wr[33] * sc); \
    wb##t##_1[2] = (__fp16)(wr[34] * sc); wb##t##_1[3] = (__fp16)(wr[35] * sc); \
    wb##t##_1[4] = (__fp16)(wr[36] * sc); wb##t##_1[5] = (__fp16)(wr[37] * sc); \
    wb##t##_1[6] = (__fp16)(wr[38] * sc); wb##t##_1[7] = (__fp16)(wr[39] * sc); \
    asm volatile("" : "+v"(wb##t##_0), "+v"(wb##t##_1)); }
    FOR16(LOADW)
#undef LOADW

    // ---- per-cell x-weights, biases, wfc (unit u = c*16+col) ----
#define DECLX(c) \
    half2v wxi##c##a, wxi##c##b, wxf##c##a, wxf##c##b; \
    half2v wxg##c##a, wxg##c##b, wxo##c##a, wxo##c##b; \
    float bi##c, bf##c, bg##c, bo##c, wq##c; float cst##c = 0.0f;
    FORC(DECLX)
#undef DECLX
#define LOADX(c) { \
    const int u = (c) * 16 + col; \
    wxi##c##a = __builtin_amdgcn_cvt_pkrtz(W_ih[(0*HN+u)*4+0]*LOG2E, W_ih[(0*HN+u)*4+1]*LOG2E); \
    wxi##c##b = __builtin_amdgcn_cvt_pkrtz(W_ih[(0*HN+u)*4+2]*LOG2E, W_ih[(0*HN+u)*4+3]*LOG2E); \
    wxf##c##a = __builtin_amdgcn_cvt_pkrtz(W_ih[(1*HN+u)*4+0]*LOG2E, W_ih[(1*HN+u)*4+1]*LOG2E); \
    wxf##c##b = __builtin_amdgcn_cvt_pkrtz(W_ih[(1*HN+u)*4+2]*LOG2E, W_ih[(1*HN+u)*4+3]*LOG2E); \
    wxg##c##a = __builtin_amdgcn_cvt_pkrtz(W_ih[(2*HN+u)*4+0]*2.0f*LOG2E, W_ih[(2*HN+u)*4+1]*2.0f*LOG2E); \
    wxg##c##b = __builtin_amdgcn_cvt_pkrtz(W_ih[(2*HN+u)*4+2]*2.0f*LOG2E, W_ih[(2*HN+u)*4+3]*2.0f*LOG2E); \
    wxo##c##a = __builtin_amdgcn_cvt_pkrtz(W_ih[(3*HN+u)*4+0]*LOG2E, W_ih[(3*HN+u)*4+1]*LOG2E); \
    wxo##c##b = __builtin_amdgcn_cvt_pkrtz(W_ih[(3*HN+u)*4+2]*LOG2E, W_ih[(3*HN+u)*4+3]*LOG2E); \
    bi##c = (b_ih[0*HN+u] + b_hh[0*HN+u]) * LOG2E; \
    bf##c = (b_ih[1*HN+u] + b_hh[1*HN+u]) * LOG2E; \
    bg##c = (b_ih[2*HN+u] + b_hh[2*HN+u]) * (2.0f*LOG2E); \
    bo##c = (b_ih[3*HN+u] + b_hh[3*HN+u]) * LOG2E; \
    wq##c = W_fc[u]; }
    FORC(LOADX)
#undef LOADX

    const float bfc = b_fc[0];
    const int   ea  = col >> 2;    // element whose h this lane's A-row needs

    // ---- x stage: lane (rg=element, col=step-in-chunk) ----
    float4 xcur = *(const float4*)(x + ((size_t)(b0 + rg) * TLEN + col) * 4);

    for (int ci = 0; ci < TLEN / 16; ++ci) {
        // publish this chunk's x to xbuf (ds_write_b64; in-order DS)
        const unsigned xi0 = (unsigned)__builtin_bit_cast(int,
                                 __builtin_amdgcn_cvt_pkrtz(xcur.x, xcur.y));
        const unsigned xi1 = (unsigned)__builtin_bit_cast(int,
                                 __builtin_amdgcn_cvt_pkrtz(xcur.z, xcur.w));
        *(uint2*)&xbuf[rg * 34 + col * 2] = make_uint2(xi0, xi1);

        const int cn = (ci < TLEN / 16 - 1) ? ci + 1 : ci;
        float4 xnext = *(const float4*)(x + ((size_t)(b0 + rg) * TLEN
                                             + cn * 16 + col) * 4);

        for (int s = 0; s < 16; ++s) {
            // ---- A fragments: element ea's h k-slices ----
            const half8v a0 = *(const half8v*)&hbuf[ea * 88 + rg * 8];
            const half8v a1 = *(const half8v*)&hbuf[ea * 88 + 32 + rg * 8];
            // ---- x_t of element rg (uniform per rg-group) ----
            const uint2 xw = *(const uint2*)&xbuf[rg * 34 + s * 2];
            const half2v xh0 = __builtin_bit_cast(half2v, (int)xw.x);
            const half2v xh1 = __builtin_bit_cast(half2v, (int)xw.y);

            // ---- x-dots: 4 cells x 4 gates x 2 fdot2 (biases in C) ----
#define XDOT(c) \
            float ai##c = __builtin_amdgcn_fdot2(wxi##c##a, xh0, bi##c, false); \
            float af##c = __builtin_amdgcn_fdot2(wxf##c##a, xh0, bf##c, false); \
            float ag##c = __builtin_amdgcn_fdot2(wxg##c##a, xh0, bg##c, false); \
            float ao##c = __builtin_amdgcn_fdot2(wxo##c##a, xh0, bo##c, false); \
            ai##c = __builtin_amdgcn_fdot2(wxi##c##b, xh1, ai##c, false); \
            af##c = __builtin_amdgcn_fdot2(wxf##c##b, xh1, af##c, false); \
            ag##c = __builtin_amdgcn_fdot2(wxg##c##b, xh1, ag##c, false); \
            ao##c = __builtin_amdgcn_fdot2(wxo##c##b, xh1, ao##c, false);
            FORC(XDOT)
#undef XDOT

            // ---- hh: 16 tiles x 2 K-halves; element rg's gates in reg 0
            const float4v zf = {0.0f, 0.0f, 0.0f, 0.0f};
#define MM(t) \
            float4v d##t = __builtin_amdgcn_mfma_f32_16x16x32_f16(a0, wb##t##_0, zf, 0, 0, 0); \
            d##t = __builtin_amdgcn_mfma_f32_16x16x32_f16(a1, wb##t##_1, d##t, 0, 0, 0);
            FOR16(MM)
#undef MM
            ai0 += d0[0];  ai1 += d1[0];  ai2 += d2[0];  ai3 += d3[0];
            af0 += d4[0];  af1 += d5[0];  af2 += d6[0];  af3 += d7[0];
            ag0 += d8[0];  ag1 += d9[0];  ag2 += d10[0]; ag3 += d11[0];
            ao0 += d12[0]; ao1 += d13[0]; ao2 += d14[0]; ao3 += d15[0];

            // ---- 4 independent act chains (latency mutually hidden) ----
#define ACT(c) \
            const float si##c = __builtin_amdgcn_rcpf(1.0f + __builtin_amdgcn_exp2f(-ai##c)); \
            const float sf##c = __builtin_amdgcn_rcpf(1.0f + __builtin_amdgcn_exp2f(-af##c)); \
            const float tg##c = 1.0f - 2.0f * __builtin_amdgcn_rcpf(1.0f + __builtin_amdgcn_exp2f(ag##c)); \
            const float so##c = __builtin_amdgcn_rcpf(1.0f + __builtin_amdgcn_exp2f(-ao##c)); \
            cst##c = sf##c * cst##c + si##c * tg##c; \
            const float th##c = 1.0f - 2.0f * __builtin_amdgcn_rcpf( \
                1.0f + __builtin_amdgcn_exp2f(cst##c * (2.0f * LOG2E))); \
            const float h##c = so##c * th##c;
            FORC(ACT)
#undef ACT

            // ---- publish h (element rg, units c*16+col), f16 RTZ ----
#define PUB(c) hbuf[rg * 88 + (c) * 16 + col] = (unsigned short) \
            (__builtin_bit_cast(int, __builtin_amdgcn_cvt_pkrtz(h##c, h##c)) & 0xffff);
            FORC(PUB)
#undef PUB

            // ---- FC partial of element rg at step s ----
            ring[s * 80 + rg * 20 + col] =
                (h0 * wq0 + h1 * wq1) + (h2 * wq2 + h3 * wq3);
        }

        // ---- chunk-end FC reduce: lane (e2=l>>4, s2=l&15) ----
        __syncthreads();   // single wave: orders ring w->r
        {
            const int e2 = l >> 4, s2 = l & 15;
            const float* rb = &ring[s2 * 80 + e2 * 20];
            const float4 r0 = *(const float4*)&rb[0];
            const float4 r1 = *(const float4*)&rb[4];
            const float4 r2 = *(const float4*)&rb[8];
            const float4 r3 = *(const float4*)&rb[12];
            const float sum = ((r0.x + r0.y) + (r0.z + r0.w))
                            + ((r1.x + r1.y) + (r1.z + r1.w))
                            + ((r2.x + r2.y) + (r2.z + r2.w))
                            + ((r3.x + r3.y) + (r3.z + r3.w));
            out[(size_t)(b0 + e2) * TLEN + ci * 16 + s2] = sum + bfc;
        }
        __syncthreads();   // ring/xbuf reads done before next chunk writes

        xcur = xnext;
    }
}

extern "C" void kernel_launch(void* const* d_in, const int* in_sizes, int n_in,
                              void* d_out, int out_size, void* d_ws, size_t ws_size,
                              hipStream_t stream) {
    const float* x    = (const float*)d_in[0];
    const float* W_ih = (const float*)d_in[1];
    const float* W_hh = (const float*)d_in[2];
    const float* b_ih = (const float*)d_in[3];
    const float* b_hh = (const float*)d_in[4];
    const float* W_fc = (const float*)d_in[5];
    const float* b_fc = (const float*)d_in[6];
    float* out = (float*)d_out;

    const int B = in_sizes[0] / (TLEN * 4);   // 1024
    lstm_e4<<<dim3(B / 4), dim3(64), 0, stream>>>(
        x, W_ih, W_hh, b_ih, b_hh, W_fc, b_fc, out);
}